// Round 5
// baseline (269.708 us; speedup 1.0000x reference)
//
#include <hip/hip_runtime.h>

// TriangleLinear: out[b][8191-r] = bias[r] + sum_{c>=max(0,r-4)} W_packed[...] * x[b][c]
// Floor: 134.4 MB weight stream / 6.3 TB/s ~= 21 us kernel. Fixed harness traffic
// ~140 us (537 MB ws poison-fill + 134 MB w-restore) rides on top of every total.
// R4 probe pinned: kernel_R3 ~= 59 us (2.3 TB/s), VALUBusy 9.6%, occupancy 42%,
// conflicts 0 => latency-bound, too few waves. Occupancy was LDS-capped (33.8 KB
// stage-1 tile -> 4 blocks/CU = 16 waves).
// R5: same streaming loop; reduction split into 2 passes over a [256][17] tile
// (17.6 KB LDS -> 8 blocks/CU) + __launch_bounds__(256,8) to pin VGPR<=64
// (R4 probe compiled at exactly 64 with MORE live pointers) -> 32 waves/CU.

constexpr int N = 8192;      // N_IN == N_OUT
constexpr int BATCH = 8;
constexpr int ROWS = 4;      // rows per block: x loads shared across rows in registers
constexpr int THREADS = 256;
constexpr int VEC = 4;       // columns per thread (float4 loads)
constexpr int TILE = THREADS * VEC;  // 1024 columns per block-iteration

// Row bases are only 4 B aligned; dwordx4 needs only dword alignment on gfx9+.
typedef float f32x4v __attribute__((ext_vector_type(4)));
typedef f32x4v __attribute__((aligned(4))) f32x4u;

__global__ __launch_bounds__(THREADS, 8)   // 8 waves/EU -> VGPR<=64, 8 blocks/CU
void tri_linear_kernel(const float* __restrict__ x,
                       const float* __restrict__ w,
                       const float* __restrict__ bias,
                       float* __restrict__ out) {
  const int t = threadIdx.x;
  const int r0 = blockIdx.x * ROWS;

  // Per-row triangular start column and packed-row base pointers (uniform -> SGPR).
  int c0[ROWS];
  const float* wrow[ROWS];
#pragma unroll
  for (int i = 0; i < ROWS; ++i) {
    const int r = r0 + i;
    c0[i] = (r > 4) ? (r - 4) : 0;
    // off(r) = 8192*r - (r-5)(r-4)/2 for r>=5, else 8192*r. (off(8192)=33,591,286 = nW)
    long long off = (r <= 5)
        ? (long long)r * N
        : (long long)r * N - ((long long)(r - 5) * (long long)(r - 4)) / 2;
    wrow[i] = w + (off - (long long)c0[i]);   // wrow[i][c] valid for c in [c0[i], N)
  }
  const int cbA = c0[0] & ~(TILE - 1);        // c0[0] == min c0 of this block's rows

  float acc[ROWS][BATCH];
#pragma unroll
  for (int i = 0; i < ROWS; ++i)
#pragma unroll
    for (int b = 0; b < BATCH; ++b) acc[i][b] = 0.0f;

  // ---- Edge tile [cbA, cbA+TILE): predicated on the triangular boundary ----
  {
    const int c = cbA + VEC * t;
    float4 xv[BATCH];
#pragma unroll
    for (int b = 0; b < BATCH; ++b)
      xv[b] = *(const float4*)(x + b * N + c);
#pragma unroll
    for (int i = 0; i < ROWS; ++i) {
#pragma unroll
      for (int j = 0; j < VEC; ++j) {
        const int cj = c + j;
        const float wv = (cj >= c0[i]) ? wrow[i][cj] : 0.0f;
#pragma unroll
        for (int b = 0; b < BATCH; ++b) {
          const float* xe = reinterpret_cast<const float*>(&xv[b]);
          acc[i][b] = fmaf(wv, xe[j], acc[i][b]);
        }
      }
    }
  }

  // ---- Main loop: predicate-free, float4 everywhere ----
  for (int cb = cbA + TILE; cb < N; cb += TILE) {
    const int c = cb + VEC * t;
    f32x4v wv[ROWS];
#pragma unroll
    for (int i = 0; i < ROWS; ++i)
      wv[i] = *(const f32x4u*)(wrow[i] + c);   // global_load_dwordx4 (align-4 legal)
    float4 xv[BATCH];
#pragma unroll
    for (int b = 0; b < BATCH; ++b)
      xv[b] = *(const float4*)(x + b * N + c); // 16 B aligned, L2-hot
#pragma unroll
    for (int i = 0; i < ROWS; ++i)
#pragma unroll
      for (int j = 0; j < VEC; ++j)
#pragma unroll
        for (int b = 0; b < BATCH; ++b) {
          const float* xe = reinterpret_cast<const float*>(&xv[b]);
          acc[i][b] = fmaf(wv[i][j], xe[j], acc[i][b]);
        }
  }

  // ---- Reduction: 32 sums, TWO passes of 16 over a [256][17] tile ----
  // LDS total = 17408 + 1088 B ~= 18 KB -> 8 blocks/CU (vs 34 KB -> 4 in R3/R4).
  // Bank math: stride 17 is odd -> stage-1 write/read and red2 access are <=2-way
  // (free on wave64).
  __shared__ float red[THREADS][17];
  __shared__ float red2[16][17];
#pragma unroll
  for (int pass = 0; pass < 2; ++pass) {
    if (pass) __syncthreads();                // protect LDS reuse across passes
#pragma unroll
    for (int i = 0; i < 2; ++i)
#pragma unroll
      for (int b = 0; b < BATCH; ++b)
        red[t][i * BATCH + b] = acc[2 * pass + i][b];
    __syncthreads();

    const int s = t & 15;       // which of this pass's 16 (row,batch) sums
    const int part = t >> 4;    // which 16-thread chunk
    float ps = 0.0f;
#pragma unroll
    for (int k = 0; k < 16; ++k) ps += red[part * 16 + k][s];
    red2[s][part] = ps;
    __syncthreads();

    if (t < 16) {
      float total = 0.0f;
#pragma unroll
      for (int g = 0; g < 16; ++g) total += red2[t][g];
      const int i = t >> 3, b = t & 7;       // t == i*BATCH + b
      const int r = r0 + 2 * pass + i;
      out[b * N + (N - 1 - r)] = total + bias[r];  // last-dim flip + bias
    }
  }
}

extern "C" void kernel_launch(void* const* d_in, const int* in_sizes, int n_in,
                              void* d_out, int out_size, void* d_ws, size_t ws_size,
                              hipStream_t stream) {
  const float* x    = (const float*)d_in[0];  // [8, 8192]
  const float* w    = (const float*)d_in[1];  // [33591286] packed triangular
  const float* bias = (const float*)d_in[2];  // [8192]
  float* out = (float*)d_out;                 // [8, 8192]
  tri_linear_kernel<<<N / ROWS, THREADS, 0, stream>>>(x, w, bias, out);
}

// Round 6
// 229.339 us; speedup vs baseline: 1.1760x; 1.1760x over previous
//
#include <hip/hip_runtime.h>

// TriangleLinear: out[b][8191-r] = bias[r] + sum_{c>=max(0,r-4)} W_packed[...] * x[b][c]
// Measured machine model (R1-R5): HBM READ-side ceiling ~3.1 TB/s (R4 probe 2.7,
// memcpy-read ~3, m13 copy 3.15/dir), writes ~7 TB/s. Kernel floor = 134.4 MB
// weight stream / 3.1 TB/s ~= 43-45 us. Fixed harness traffic ~140 us/replay.
// Occupancy is NOT the binder (R1 4 waves/CU == R3 16 waves/CU == ~60 us).
// R5 FAILED: launch_bounds(256,8) -> VGPR cap 64 < ~110 live -> scratch spills
// (WRITE_SIZE 190 MB) -> 133 us. Lesson: never cap below live-set.
// R6: ROWS 4->8. Halves the L2-hit x traffic (537->268 MB) that dilutes HBM
// request density (w:x VMEM ratio 1:2 -> 1:1); doubles FMA per w-byte.

constexpr int N = 8192;      // N_IN == N_OUT
constexpr int BATCH = 8;
constexpr int ROWS = 8;      // rows per block: x loads shared across 8 rows
constexpr int THREADS = 256;
constexpr int VEC = 4;       // columns per thread (float4 loads)
constexpr int TILE = THREADS * VEC;  // 1024 columns per block-iteration

// Row bases are only 4 B aligned; dwordx4 needs only dword alignment on gfx9+.
typedef float f32x4v __attribute__((ext_vector_type(4)));
typedef f32x4v __attribute__((aligned(4))) f32x4u;

__global__ __launch_bounds__(THREADS, 4)   // VGPR cap 128 >> ~120 live: no spills
void tri_linear_kernel(const float* __restrict__ x,
                       const float* __restrict__ w,
                       const float* __restrict__ bias,
                       float* __restrict__ out) {
  const int t = threadIdx.x;
  const int r0 = blockIdx.x * ROWS;

  // Per-row triangular start column and packed-row base pointers (uniform -> SGPR).
  int c0[ROWS];
  const float* wrow[ROWS];
#pragma unroll
  for (int i = 0; i < ROWS; ++i) {
    const int r = r0 + i;
    c0[i] = (r > 4) ? (r - 4) : 0;
    // off(r) = 8192*r - (r-5)(r-4)/2 for r>=5, else 8192*r. (off(8192)=33,591,286 = nW)
    long long off = (r <= 5)
        ? (long long)r * N
        : (long long)r * N - ((long long)(r - 5) * (long long)(r - 4)) / 2;
    wrow[i] = w + (off - (long long)c0[i]);   // wrow[i][c] valid for c in [c0[i], N)
  }
  const int cbA = c0[0] & ~(TILE - 1);                 // first tile touched
  const int cbM = (c0[ROWS - 1] + TILE - 1) & ~(TILE - 1);  // first FULL tile
  // NOTE: with ROWS=8 the row-spread (7) can straddle a tile boundary, so the
  // predicated edge region [cbA, cbM) may be 1 OR 2 tiles -> loop, don't assume 1.

  float acc[ROWS][BATCH];
#pragma unroll
  for (int i = 0; i < ROWS; ++i)
#pragma unroll
    for (int b = 0; b < BATCH; ++b) acc[i][b] = 0.0f;

  // ---- Edge tiles [cbA, cbM): predicated on the triangular boundary ----
  for (int cb = cbA; cb < cbM; cb += TILE) {
    const int c = cb + VEC * t;
    float4 xv[BATCH];
#pragma unroll
    for (int b = 0; b < BATCH; ++b)
      xv[b] = *(const float4*)(x + b * N + c);
#pragma unroll
    for (int i = 0; i < ROWS; ++i) {
#pragma unroll
      for (int j = 0; j < VEC; ++j) {
        const int cj = c + j;
        const float wv = (cj >= c0[i]) ? wrow[i][cj] : 0.0f;
#pragma unroll
        for (int b = 0; b < BATCH; ++b) {
          const float* xe = reinterpret_cast<const float*>(&xv[b]);
          acc[i][b] = fmaf(wv, xe[j], acc[i][b]);
        }
      }
    }
  }

  // ---- Main loop: predicate-free; 8 w loads + 8 x loads per iter (1:1) ----
  for (int cb = cbM; cb < N; cb += TILE) {
    const int c = cb + VEC * t;
    float4 xv[BATCH];
#pragma unroll
    for (int b = 0; b < BATCH; ++b)
      xv[b] = *(const float4*)(x + b * N + c);   // 16 B aligned, L2-hot
#pragma unroll
    for (int i = 0; i < ROWS; ++i) {
      const f32x4v wv = *(const f32x4u*)(wrow[i] + c);  // dwordx4, align-4 legal
#pragma unroll
      for (int j = 0; j < VEC; ++j)
#pragma unroll
        for (int b = 0; b < BATCH; ++b) {
          const float* xe = reinterpret_cast<const float*>(&xv[b]);
          acc[i][b] = fmaf(wv[j], xe[j], acc[i][b]);
        }
    }
  }

  // ---- Reduction: 64 sums, FOUR passes of 16 over an 18.5 KB tile ----
  // (R5's spill-free two-stage pattern, extended to ROWS=8.)
  __shared__ float red[THREADS][17];
  __shared__ float red2[16][17];
#pragma unroll
  for (int pass = 0; pass < 4; ++pass) {
    if (pass) __syncthreads();                // protect LDS reuse across passes
#pragma unroll
    for (int i = 0; i < 2; ++i)
#pragma unroll
      for (int b = 0; b < BATCH; ++b)
        red[t][i * BATCH + b] = acc[2 * pass + i][b];
    __syncthreads();

    const int s = t & 15;       // which of this pass's 16 (row,batch) sums
    const int part = t >> 4;    // which 16-thread chunk
    float ps = 0.0f;
#pragma unroll
    for (int k = 0; k < 16; ++k) ps += red[part * 16 + k][s];
    red2[s][part] = ps;
    __syncthreads();

    if (t < 16) {
      float total = 0.0f;
#pragma unroll
      for (int g = 0; g < 16; ++g) total += red2[t][g];
      const int i = t >> 3, b = t & 7;       // t == i*BATCH + b
      const int r = r0 + 2 * pass + i;
      out[b * N + (N - 1 - r)] = total + bias[r];  // last-dim flip + bias
    }
  }
}

extern "C" void kernel_launch(void* const* d_in, const int* in_sizes, int n_in,
                              void* d_out, int out_size, void* d_ws, size_t ws_size,
                              hipStream_t stream) {
  const float* x    = (const float*)d_in[0];  // [8, 8192]
  const float* w    = (const float*)d_in[1];  // [33591286] packed triangular
  const float* bias = (const float*)d_in[2];  // [8192]
  float* out = (float*)d_out;                 // [8, 8192]
  tri_linear_kernel<<<N / ROWS, THREADS, 0, stream>>>(x, w, bias, out);
}

// Round 7
// 200.392 us; speedup vs baseline: 1.3459x; 1.1445x over previous
//
#include <hip/hip_runtime.h>

// TriangleLinear: out[b][8191-r] = bias[r] + sum_{c>=max(0,r-4)} W_packed[...] * x[b][c]
// Measured machine model (R1-R6):
//  - Aggregate demand-side (L1/L2 request) ceiling ~11 TB/s: R3 671 MB/59us=11.4,
//    R4 probe 1.2 GB/121us=10.0. This, not HBM alone, is the binder.
//  - Fixed harness traffic ~140 us/replay (537 MB ws poison-fill + w restore).
//  - Occupancy NOT a binder in 4..16 waves/CU (R1==R3==~60 us).
//  - SPILLS are the recurring killer: __launch_bounds__(256,4) -> allocator
//    targets VGPR=64 (measured R4/R6; (256,8)->32 in R5) < live set -> 92-190 MB
//    scratch traffic. Lesson: the 2nd arg behaves 2x tighter than the
//    waves-per-EU formula suggests on this toolchain.
// R7 = R6 (ROWS=8, demand 402 MB -> ~37 us at 11 TB/s) with launch_bounds(256,2)
// so the ~110-reg live set fits spill-free.

constexpr int N = 8192;      // N_IN == N_OUT
constexpr int BATCH = 8;
constexpr int ROWS = 8;      // rows per block: x loads shared across 8 rows
constexpr int THREADS = 256;
constexpr int VEC = 4;       // columns per thread (float4 loads)
constexpr int TILE = THREADS * VEC;  // 1024 columns per block-iteration

// Row bases are only 4 B aligned; dwordx4 needs only dword alignment on gfx9+.
typedef float f32x4v __attribute__((ext_vector_type(4)));
typedef f32x4v __attribute__((aligned(4))) f32x4u;

__global__ __launch_bounds__(THREADS, 2)   // loose cap: ~110 live regs, no spills
void tri_linear_kernel(const float* __restrict__ x,
                       const float* __restrict__ w,
                       const float* __restrict__ bias,
                       float* __restrict__ out) {
  const int t = threadIdx.x;
  const int r0 = blockIdx.x * ROWS;

  // Per-row triangular start column and packed-row base pointers (uniform -> SGPR).
  int c0[ROWS];
  const float* wrow[ROWS];
#pragma unroll
  for (int i = 0; i < ROWS; ++i) {
    const int r = r0 + i;
    c0[i] = (r > 4) ? (r - 4) : 0;
    // off(r) = 8192*r - (r-5)(r-4)/2 for r>=5, else 8192*r. (off(8192)=33,591,286 = nW)
    long long off = (r <= 5)
        ? (long long)r * N
        : (long long)r * N - ((long long)(r - 5) * (long long)(r - 4)) / 2;
    wrow[i] = w + (off - (long long)c0[i]);   // wrow[i][c] valid for c in [c0[i], N)
  }
  const int cbA = c0[0] & ~(TILE - 1);                 // first tile touched
  const int cbM = (c0[ROWS - 1] + TILE - 1) & ~(TILE - 1);  // first FULL tile
  // ROWS=8 row-spread can straddle a tile boundary: edge region is 1 OR 2 tiles.

  float acc[ROWS][BATCH];
#pragma unroll
  for (int i = 0; i < ROWS; ++i)
#pragma unroll
    for (int b = 0; b < BATCH; ++b) acc[i][b] = 0.0f;

  // ---- Edge tiles [cbA, cbM): predicated on the triangular boundary ----
  for (int cb = cbA; cb < cbM; cb += TILE) {
    const int c = cb + VEC * t;
    float4 xv[BATCH];
#pragma unroll
    for (int b = 0; b < BATCH; ++b)
      xv[b] = *(const float4*)(x + b * N + c);
#pragma unroll
    for (int i = 0; i < ROWS; ++i) {
#pragma unroll
      for (int j = 0; j < VEC; ++j) {
        const int cj = c + j;
        const float wv = (cj >= c0[i]) ? wrow[i][cj] : 0.0f;
#pragma unroll
        for (int b = 0; b < BATCH; ++b) {
          const float* xe = reinterpret_cast<const float*>(&xv[b]);
          acc[i][b] = fmaf(wv, xe[j], acc[i][b]);
        }
      }
    }
  }

  // ---- Main loop: predicate-free; 8 w loads + 8 x loads per iter (1:1) ----
  for (int cb = cbM; cb < N; cb += TILE) {
    const int c = cb + VEC * t;
    float4 xv[BATCH];
#pragma unroll
    for (int b = 0; b < BATCH; ++b)
      xv[b] = *(const float4*)(x + b * N + c);   // 16 B aligned, L2-hot
#pragma unroll
    for (int i = 0; i < ROWS; ++i) {
      const f32x4v wv = *(const f32x4u*)(wrow[i] + c);  // dwordx4, align-4 legal
#pragma unroll
      for (int j = 0; j < VEC; ++j)
#pragma unroll
        for (int b = 0; b < BATCH; ++b) {
          const float* xe = reinterpret_cast<const float*>(&xv[b]);
          acc[i][b] = fmaf(wv[j], xe[j], acc[i][b]);
        }
    }
  }

  // ---- Reduction: 64 sums, FOUR passes of 16 over an 18.5 KB tile ----
  __shared__ float red[THREADS][17];
  __shared__ float red2[16][17];
#pragma unroll
  for (int pass = 0; pass < 4; ++pass) {
    if (pass) __syncthreads();                // protect LDS reuse across passes
#pragma unroll
    for (int i = 0; i < 2; ++i)
#pragma unroll
      for (int b = 0; b < BATCH; ++b)
        red[t][i * BATCH + b] = acc[2 * pass + i][b];
    __syncthreads();

    const int s = t & 15;       // which of this pass's 16 (row,batch) sums
    const int part = t >> 4;    // which 16-thread chunk
    float ps = 0.0f;
#pragma unroll
    for (int k = 0; k < 16; ++k) ps += red[part * 16 + k][s];
    red2[s][part] = ps;
    __syncthreads();

    if (t < 16) {
      float total = 0.0f;
#pragma unroll
      for (int g = 0; g < 16; ++g) total += red2[t][g];
      const int i = t >> 3, b = t & 7;       // t == i*BATCH + b
      const int r = r0 + 2 * pass + i;
      out[b * N + (N - 1 - r)] = total + bias[r];  // last-dim flip + bias
    }
  }
}

extern "C" void kernel_launch(void* const* d_in, const int* in_sizes, int n_in,
                              void* d_out, int out_size, void* d_ws, size_t ws_size,
                              hipStream_t stream) {
  const float* x    = (const float*)d_in[0];  // [8, 8192]
  const float* w    = (const float*)d_in[1];  // [33591286] packed triangular
  const float* bias = (const float*)d_in[2];  // [8192]
  float* out = (float*)d_out;                 // [8, 8192]
  tri_linear_kernel<<<N / ROWS, THREADS, 0, stream>>>(x, w, bias, out);
}